// Round 7
// baseline (110.528 us; speedup 1.0000x reference)
//
#include <hip/hip_runtime.h>

// VOCAB=1e6, DIM=64, BAGS=16384, N_IDX=819200, CAT_DIM=128.
// Output row = [eb(64) | eb(64) | cat(128)] = 256 f32.
//
// R7: repack-ALL streaming pipeline (R6 minus its self-inflicted overheads:
// no flags, no hipMemsetAsync, no random byte-writes).
//  1) init: output cols 0..127 zero, 128..255 = cat.
//  2) repack: ALL 1M rows, pure streaming: read 256MB @ ~7TB/s, write 32MB
//     (4-bit nibbles: 8 dwords per 64-dim row).
//  3) gather: R4 burst structure, but each row costs 32B (broadcast dword per
//     8 lanes) from the L2/L3-resident packed table instead of 256B random HBM.
// Flushes stay wave-coalesced 256B atomics.

constexpr int CHUNK = 50;
constexpr int GROUP = 25;

__device__ __forceinline__ float readlane_f(float x, int k) {
    return __int_as_float(__builtin_amdgcn_readlane(__float_as_int(x), k));
}

__device__ __forceinline__ int detect_sh(const unsigned int* p) {
    // int64 vs int32 layout (LE): high words of first 4 indices == 0.
    return ((p[1] | p[3] | p[5] | p[7]) == 0u) ? 1 : 0;
}

__global__ __launch_bounds__(256) void init_out_kernel(
    const float* __restrict__ cat, float* __restrict__ out, int total)
{
    int t = blockIdx.x * 256 + threadIdx.x;   // total = num_bags*256
    if (t >= total) return;
    int b = t >> 8, c = t & 255;
    out[t] = (c < 128) ? 0.0f : cat[(b << 7) + (c - 128)];
}

// Pack 64 int32 codes -> 8 dwords per row, ALL rows, streaming.
// Thread t handles part (t&7) of row (t>>3): reads 32B, writes 4B.
__global__ __launch_bounds__(256) void repack_all_kernel(
    const int* __restrict__ wq, unsigned int* __restrict__ packed, int nparts)
{
    const int t = blockIdx.x * 256 + threadIdx.x;
    if (t >= nparts) return;
    const int* src = wq + ((long long)t << 3);      // 8 ints = 32B
    const int4 q0 = *(const int4*)(src);
    const int4 q1 = *(const int4*)(src + 4);
    const unsigned int p =
          (unsigned)(q0.x & 15)        | ((unsigned)(q0.y & 15) << 4)
        | ((unsigned)(q0.z & 15) << 8) | ((unsigned)(q0.w & 15) << 12)
        | ((unsigned)(q1.x & 15) << 16)| ((unsigned)(q1.y & 15) << 20)
        | ((unsigned)(q1.z & 15) << 24)| ((unsigned)(q1.w & 15) << 28);
    packed[t] = p;
}

// Gather on packed table (R4 structure: CHUNK=50 per wave, burst GROUP=25).
// dim = lane; lane reads dword (lane>>3) of the row, nibble (lane&7).
__global__ __launch_bounds__(256) void embag_packed_kernel(
    const unsigned int* __restrict__ packed,
    const float* __restrict__ scales,
    const float* __restrict__ biases,
    const unsigned int* __restrict__ idx32,
    const unsigned int* __restrict__ off32,
    float* __restrict__ out, int num_bags, int n_idx)
{
    const int sh = detect_sh(idx32);
    const int lane = threadIdx.x & 63;
    const int wid  = blockIdx.x * 4 + (threadIdx.x >> 6);
    const long long base = (long long)wid * CHUNK;
    if (base >= n_idx) return;
    const int i0  = (int)base;
    const int cnt = min(CHUNK, n_idx - i0);

    const int li = i0 + min(lane, cnt - 1);
    const int myidx = (int)idx32[(unsigned)li << sh];
    const float mys = scales[myidx];
    const float myb = biases[myidx];

    int lo = 0, hi = num_bags - 1;
    while (lo < hi) {
        int mid = (lo + hi) >> 1;
        if ((int)off32[(unsigned)(mid + 1) << sh] > i0) hi = mid; else lo = mid + 1;
    }
    int b = lo;
    int bend = (int)off32[(unsigned)(b + 1) << sh];

    float acc = 0.f, ab = 0.f;
    const int word = lane >> 3;               // dword of the row I read
    const unsigned int nsh = (lane & 7) * 4;  // my nibble (dim = lane)

    for (int g = 0; g < CHUNK; g += GROUP) {
        unsigned int q[GROUP];
        #pragma unroll
        for (int k = 0; k < GROUP; ++k) {
            const int ik = __builtin_amdgcn_readlane(myidx, g + k); // SGPR
            q[k] = packed[((long long)(unsigned)ik << 3) + word];   // 32B/row
        }
        #pragma unroll
        for (int k = 0; k < GROUP; ++k) {
            const int j = i0 + g + k;
            if (j >= n_idx) break;
            if (j >= bend) {
                const float v = acc + ab;
                float* p = out + ((long long)b << 8) + lane;
                atomicAdd(p, v);
                atomicAdd(p + 64, v);
                acc = 0.f; ab = 0.f;
                do { ++b; bend = (int)off32[(unsigned)(b + 1) << sh]; } while (bend <= j);
            }
            const float c = (float)((q[k] >> nsh) & 15u);
            acc = fmaf(c, readlane_f(mys, g + k), acc);
            ab += readlane_f(myb, g + k);
        }
    }
    const float v = acc + ab;
    float* p = out + ((long long)b << 8) + lane;
    atomicAdd(p, v);
    atomicAdd(p + 64, v);
}

// Fallback (R4): direct gather on the raw table when ws is too small.
__global__ __launch_bounds__(256) void embag_kernel(
    const int* __restrict__ wq,
    const float* __restrict__ scales,
    const float* __restrict__ biases,
    const unsigned int* __restrict__ idx32,
    const unsigned int* __restrict__ off32,
    float* __restrict__ out, int num_bags, int n_idx)
{
    const int sh = detect_sh(idx32);
    const int lane = threadIdx.x & 63;
    const int wid  = blockIdx.x * 4 + (threadIdx.x >> 6);
    const long long base = (long long)wid * CHUNK;
    if (base >= n_idx) return;
    const int i0  = (int)base;
    const int cnt = min(CHUNK, n_idx - i0);

    const int li = i0 + min(lane, cnt - 1);
    const int myidx = (int)idx32[(unsigned)li << sh];
    const float mys = scales[myidx];
    const float myb = biases[myidx];

    int lo = 0, hi = num_bags - 1;
    while (lo < hi) {
        int mid = (lo + hi) >> 1;
        if ((int)off32[(unsigned)(mid + 1) << sh] > i0) hi = mid; else lo = mid + 1;
    }
    int b = lo;
    int bend = (int)off32[(unsigned)(b + 1) << sh];

    float acc = 0.f, ab = 0.f;
    const char* wqb = (const char*)wq + (lane << 2);

    for (int g = 0; g < CHUNK; g += GROUP) {
        int q[GROUP];
        #pragma unroll
        for (int k = 0; k < GROUP; ++k) {
            const int ik = __builtin_amdgcn_readlane(myidx, g + k);
            q[k] = *(const int*)(wqb + ((long long)ik << 8));
        }
        #pragma unroll
        for (int k = 0; k < GROUP; ++k) {
            const int j = i0 + g + k;
            if (j >= n_idx) break;
            if (j >= bend) {
                const float v = acc + ab;
                float* p = out + ((long long)b << 8) + lane;
                atomicAdd(p, v);
                atomicAdd(p + 64, v);
                acc = 0.f; ab = 0.f;
                do { ++b; bend = (int)off32[(unsigned)(b + 1) << sh]; } while (bend <= j);
            }
            acc = fmaf((float)q[k], readlane_f(mys, g + k), acc);
            ab += readlane_f(myb, g + k);
        }
    }
    const float v = acc + ab;
    float* p = out + ((long long)b << 8) + lane;
    atomicAdd(p, v);
    atomicAdd(p + 64, v);
}

extern "C" void kernel_launch(void* const* d_in, const int* in_sizes, int n_in,
                              void* d_out, int out_size, void* d_ws, size_t ws_size,
                              hipStream_t stream) {
    const int*          wq     = (const int*)d_in[0];
    const float*        scales = (const float*)d_in[1];
    const float*        biases = (const float*)d_in[2];
    const unsigned int* idx32  = (const unsigned int*)d_in[3];
    const unsigned int* off32  = (const unsigned int*)d_in[4];
    const float*        cat    = (const float*)d_in[5];
    float*              out    = (float*)d_out;

    const int num_bags = in_sizes[5] / 128;       // 16384
    const int n_idx    = in_sizes[3];             // 819200
    const int vocab    = in_sizes[1];             // 1e6
    const int total    = num_bags * 256;

    const int nchunks = (n_idx + CHUNK - 1) / CHUNK;   // 16384 waves
    const int gblocks = (nchunks + 3) / 4;             // 4096

    init_out_kernel<<<(total + 255) / 256, 256, 0, stream>>>(cat, out, total);

    const size_t need = (size_t)vocab * 32;            // packed table bytes
    if (ws_size >= need) {
        unsigned int* packed = (unsigned int*)d_ws;
        const int nparts = vocab * 8;                  // 8M parts
        repack_all_kernel<<<(nparts + 255) / 256, 256, 0, stream>>>(
            wq, packed, nparts);
        embag_packed_kernel<<<gblocks, 256, 0, stream>>>(
            packed, scales, biases, idx32, off32, out, num_bags, n_idx);
    } else {
        embag_kernel<<<gblocks, 256, 0, stream>>>(
            wq, scales, biases, idx32, off32, out, num_bags, n_idx);
    }
}

// Round 8
// 73.172 us; speedup vs baseline: 1.5105x; 1.5105x over previous
//
#include <hip/hip_runtime.h>

// VOCAB=1e6, DIM=64, BAGS=16384, N_IDX=819200, CAT_DIM=128.
// Output row = [eb(64) | eb(64) | cat(128)] = 256 f32.
//
// R8 = R4's gather (best measured: random 256B row gather @ ~3.3 TB/s,
// insensitive to burst depth/instruction count per R2/R4/R5) with the
// non-gather overhead stripped:
//  1) zero_ws: 4MB [BAGS,64] f32 accumulator (float4 stores, ~1us).
//  2) embag:   R4 structure; flush = ONE 256B wave-coalesced atomic into ws
//              (was two into out; out no longer needs pre-init).
//  3) finalize: wave per bag; plain coalesced stores of the 1KB output row
//              (eb, eb copy, cat) - no atomics on d_out.

constexpr int CHUNK = 50;
constexpr int GROUP = 25;

__device__ __forceinline__ float readlane_f(float x, int k) {
    return __int_as_float(__builtin_amdgcn_readlane(__float_as_int(x), k));
}

__device__ __forceinline__ int detect_sh(const unsigned int* p) {
    // int64 vs int32 layout (LE): high words of first 4 indices == 0.
    return ((p[1] | p[3] | p[5] | p[7]) == 0u) ? 1 : 0;
}

__global__ __launch_bounds__(256) void zero_ws_kernel(
    float4* __restrict__ ws, int n4)
{
    const int t = blockIdx.x * 256 + threadIdx.x;
    if (t < n4) ws[t] = make_float4(0.f, 0.f, 0.f, 0.f);
}

__global__ __launch_bounds__(256) void embag_ws_kernel(
    const int* __restrict__ wq,             // [VOCAB, 64] int32 codes
    const float* __restrict__ scales,       // [VOCAB]
    const float* __restrict__ biases,       // [VOCAB]
    const unsigned int* __restrict__ idx32, // indices viewed as u32 words
    const unsigned int* __restrict__ off32, // offsets viewed as u32 words
    float* __restrict__ ws,                 // [BAGS, 64] accumulator
    int num_bags, int n_idx)
{
    const int sh = detect_sh(idx32);
    const int lane = threadIdx.x & 63;
    const int wid  = blockIdx.x * 4 + (threadIdx.x >> 6);
    const long long base = (long long)wid * CHUNK;
    if (base >= n_idx) return;
    const int i0  = (int)base;
    const int cnt = min(CHUNK, n_idx - i0);

    // Per-lane prefetch of idx/scale/bias for the whole chunk.
    const int li = i0 + min(lane, cnt - 1);
    const int myidx = (int)idx32[(unsigned)li << sh];
    const float mys = scales[myidx];
    const float myb = biases[myidx];

    // Start bag: smallest b with off[b+1] > i0 (searchsorted-right).
    int lo = 0, hi = num_bags - 1;
    while (lo < hi) {
        int mid = (lo + hi) >> 1;
        if ((int)off32[(unsigned)(mid + 1) << sh] > i0) hi = mid; else lo = mid + 1;
    }
    int b = lo;
    int bend = (int)off32[(unsigned)(b + 1) << sh];

    float acc = 0.f, ab = 0.f;
    const char* wqb = (const char*)wq + (lane << 2);

    for (int g = 0; g < CHUNK; g += GROUP) {
        // Burst-issue GROUP independent 256B row gathers (readlane -> SGPR).
        int q[GROUP];
        #pragma unroll
        for (int k = 0; k < GROUP; ++k) {
            const int ik = __builtin_amdgcn_readlane(myidx, g + k);
            q[k] = *(const int*)(wqb + ((long long)ik << 8));
        }
        // Consume with boundary flushes.
        #pragma unroll
        for (int k = 0; k < GROUP; ++k) {
            const int j = i0 + g + k;
            if (j >= n_idx) break;
            if (j >= bend) {
                atomicAdd(ws + ((long long)b << 6) + lane, acc + ab);
                acc = 0.f; ab = 0.f;
                do { ++b; bend = (int)off32[(unsigned)(b + 1) << sh]; } while (bend <= j);
            }
            acc = fmaf((float)q[k], readlane_f(mys, g + k), acc);
            ab += readlane_f(myb, g + k);
        }
    }
    atomicAdd(ws + ((long long)b << 6) + lane, acc + ab);
}

// Wave per bag: read 256B acc row, write the full 1KB output row.
__global__ __launch_bounds__(256) void finalize_kernel(
    const float* __restrict__ ws, const float* __restrict__ cat,
    float* __restrict__ out, int num_bags)
{
    const int lane = threadIdx.x & 63;
    const int b = blockIdx.x * 4 + (threadIdx.x >> 6);
    if (b >= num_bags) return;
    const float v = ws[((long long)b << 6) + lane];
    float* orow = out + ((long long)b << 8);
    orow[lane]       = v;
    orow[64 + lane]  = v;
    orow[128 + lane] = cat[(b << 7) + lane];
    orow[192 + lane] = cat[(b << 7) + 64 + lane];
}

// Fallback (R4 verbatim) when ws is too small: init + direct atomics on out.
__global__ __launch_bounds__(256) void init_out_kernel(
    const float* __restrict__ cat, float* __restrict__ out, int total)
{
    int t = blockIdx.x * 256 + threadIdx.x;
    if (t >= total) return;
    int b = t >> 8, c = t & 255;
    out[t] = (c < 128) ? 0.0f : cat[(b << 7) + (c - 128)];
}

__global__ __launch_bounds__(256) void embag_kernel(
    const int* __restrict__ wq,
    const float* __restrict__ scales,
    const float* __restrict__ biases,
    const unsigned int* __restrict__ idx32,
    const unsigned int* __restrict__ off32,
    float* __restrict__ out, int num_bags, int n_idx)
{
    const int sh = detect_sh(idx32);
    const int lane = threadIdx.x & 63;
    const int wid  = blockIdx.x * 4 + (threadIdx.x >> 6);
    const long long base = (long long)wid * CHUNK;
    if (base >= n_idx) return;
    const int i0  = (int)base;
    const int cnt = min(CHUNK, n_idx - i0);

    const int li = i0 + min(lane, cnt - 1);
    const int myidx = (int)idx32[(unsigned)li << sh];
    const float mys = scales[myidx];
    const float myb = biases[myidx];

    int lo = 0, hi = num_bags - 1;
    while (lo < hi) {
        int mid = (lo + hi) >> 1;
        if ((int)off32[(unsigned)(mid + 1) << sh] > i0) hi = mid; else lo = mid + 1;
    }
    int b = lo;
    int bend = (int)off32[(unsigned)(b + 1) << sh];

    float acc = 0.f, ab = 0.f;
    const char* wqb = (const char*)wq + (lane << 2);

    for (int g = 0; g < CHUNK; g += GROUP) {
        int q[GROUP];
        #pragma unroll
        for (int k = 0; k < GROUP; ++k) {
            const int ik = __builtin_amdgcn_readlane(myidx, g + k);
            q[k] = *(const int*)(wqb + ((long long)ik << 8));
        }
        #pragma unroll
        for (int k = 0; k < GROUP; ++k) {
            const int j = i0 + g + k;
            if (j >= n_idx) break;
            if (j >= bend) {
                const float v = acc + ab;
                float* p = out + ((long long)b << 8) + lane;
                atomicAdd(p, v);
                atomicAdd(p + 64, v);
                acc = 0.f; ab = 0.f;
                do { ++b; bend = (int)off32[(unsigned)(b + 1) << sh]; } while (bend <= j);
            }
            acc = fmaf((float)q[k], readlane_f(mys, g + k), acc);
            ab += readlane_f(myb, g + k);
        }
    }
    const float v = acc + ab;
    float* p = out + ((long long)b << 8) + lane;
    atomicAdd(p, v);
    atomicAdd(p + 64, v);
}

extern "C" void kernel_launch(void* const* d_in, const int* in_sizes, int n_in,
                              void* d_out, int out_size, void* d_ws, size_t ws_size,
                              hipStream_t stream) {
    const int*          wq     = (const int*)d_in[0];
    const float*        scales = (const float*)d_in[1];
    const float*        biases = (const float*)d_in[2];
    const unsigned int* idx32  = (const unsigned int*)d_in[3];
    const unsigned int* off32  = (const unsigned int*)d_in[4];
    const float*        cat    = (const float*)d_in[5];
    float*              out    = (float*)d_out;

    const int num_bags = in_sizes[5] / 128;       // 16384
    const int n_idx    = in_sizes[3];             // 819200

    const int nchunks = (n_idx + CHUNK - 1) / CHUNK;   // 16384 waves
    const int gblocks = (nchunks + 3) / 4;             // 4096
    const int bblocks = (num_bags + 3) / 4;            // 4096

    const size_t need = (size_t)num_bags * 64 * sizeof(float);  // 4MB
    if (ws_size >= need) {
        float* wsacc = (float*)d_ws;
        const int n4 = num_bags * 16;                   // float4 count
        zero_ws_kernel<<<(n4 + 255) / 256, 256, 0, stream>>>((float4*)wsacc, n4);
        embag_ws_kernel<<<gblocks, 256, 0, stream>>>(
            wq, scales, biases, idx32, off32, wsacc, num_bags, n_idx);
        finalize_kernel<<<bblocks, 256, 0, stream>>>(wsacc, cat, out, num_bags);
    } else {
        const int total = num_bags * 256;
        init_out_kernel<<<(total + 255) / 256, 256, 0, stream>>>(cat, out, total);
        embag_kernel<<<gblocks, 256, 0, stream>>>(
            wq, scales, biases, idx32, off32, out, num_bags, n_idx);
    }
}